// Round 1
// baseline (3950.634 us; speedup 1.0000x reference)
//
#include <hip/hip_runtime.h>

constexpr int BT = 256;   // threads per block == rows per block

__device__ __forceinline__ float lrelu(float x) { return x >= 0.f ? x : 0.05f * x; }

// LDS tile: 256 rows x 64 words, word index XOR-swizzled by (row&31) so that
// "all lanes read own row at same k" is a 2-way (free) bank pattern.
__device__ __forceinline__ int swz(int row, int k) { return (row << 6) + (k ^ (row & 31)); }

// Coalesced global->LDS staging of nr rows of DIN floats (DIN % 4 == 0).
// float4 global loads; components permuted so the quad lands at the swizzled spot.
template<int DIN>
__device__ __forceinline__ void stage_rows(const float* __restrict__ g, int nr, float* __restrict__ lx)
{
    const int total = nr * DIN;
    for (int idx = threadIdx.x * 4; idx < total; idx += BT * 4) {
        const float4 vv = *reinterpret_cast<const float4*>(g + idx);
        const int row = idx / DIN;
        const int k = idx - row * DIN;
        const int m = row & 31, p = m & 3;
        // s[j] = v[j ^ p] via selects (no dynamic register indexing)
        const float e0 = (p & 2) ? vv.z : vv.x;
        const float e1 = (p & 2) ? vv.w : vv.y;
        const float e2 = (p & 2) ? vv.x : vv.z;
        const float e3 = (p & 2) ? vv.y : vv.w;
        const float f0 = (p & 1) ? e1 : e0;
        const float f1 = (p & 1) ? e0 : e1;
        const float f2 = (p & 1) ? e3 : e2;
        const float f3 = (p & 1) ? e2 : e3;
        const int q = (row << 6) + ((k ^ m) & ~3);
        *reinterpret_cast<float4*>(lx + q) = make_float4(f0, f1, f2, f3);
    }
}

// acc[j] += sum_k x[row][k] * W[k*64+j].  W accesses are wave-uniform -> s_load.
template<int DIN>
__device__ __forceinline__ void accum(const float* __restrict__ lx, int row,
                                      const float* __restrict__ W, float* __restrict__ acc)
{
    const int base = row << 6, m = row & 31;
    #pragma unroll 4
    for (int k = 0; k < DIN; ++k) {
        const float xv = lx[base + (k ^ m)];
        const float* wr = W + k * 64;
        #pragma unroll
        for (int j = 0; j < 64; ++j)
            acc[j] = fmaf(xv, wr[j], acc[j]);
    }
}

__device__ __forceinline__ void layernorm(float* __restrict__ a,
                                          const float* __restrict__ g, const float* __restrict__ be)
{
    float mu = 0.f;
    #pragma unroll
    for (int j = 0; j < 64; ++j) mu += a[j];
    mu *= 0.015625f;
    float var = 0.f;
    #pragma unroll
    for (int j = 0; j < 64; ++j) { const float d = a[j] - mu; var = fmaf(d, d, var); }
    var *= 0.015625f;
    const float rs = rsqrtf(var + 1e-5f);
    #pragma unroll
    for (int j = 0; j < 64; ++j) a[j] = (a[j] - mu) * rs * g[j] + be[j];
}

__device__ __forceinline__ void store_row64(float* __restrict__ dst, const float* __restrict__ a)
{
    #pragma unroll
    for (int q = 0; q < 16; ++q)
        reinterpret_cast<float4*>(dst)[q] = make_float4(a[4*q], a[4*q+1], a[4*q+2], a[4*q+3]);
}

// ---------------- encoder (2-layer MLP + LN), DIN in {16, 8} ----------------
template<int DIN>
__global__ __launch_bounds__(BT, 2) void k_encode(
    const float* __restrict__ x,
    const float* __restrict__ W1, const float* __restrict__ b1,
    const float* __restrict__ W2, const float* __restrict__ b2,
    const float* __restrict__ g, const float* __restrict__ be,
    float* __restrict__ out, int nrows)
{
    __shared__ float lx[BT * 64];
    const int row0 = blockIdx.x * BT;
    const int nr = min(BT, nrows - row0);
    stage_rows<DIN>(x + (long long)row0 * DIN, nr, lx);
    __syncthreads();
    const int row = threadIdx.x;
    if (row >= nr) return;
    float acc[64];
    #pragma unroll
    for (int j = 0; j < 64; ++j) acc[j] = b1[j];
    accum<DIN>(lx, row, W1, acc);
    const int base = row << 6, m = row & 31;
    #pragma unroll
    for (int k = 0; k < 64; ++k) lx[base + (k ^ m)] = lrelu(acc[k]);
    #pragma unroll
    for (int j = 0; j < 64; ++j) acc[j] = b2[j];
    accum<64>(lx, row, W2, acc);
    #pragma unroll
    for (int j = 0; j < 64; ++j) acc[j] = lrelu(acc[j]);
    layernorm(acc, g, be);
    store_row64(out + (long long)(row0 + row) * 64, acc);
}

// ---------------- u = n@B, v = n@C (edge-MLP W1 partial products) ----------------
__global__ __launch_bounds__(BT, 2) void k_uv(
    const float* __restrict__ n, const float* __restrict__ Wb, const float* __restrict__ Wc,
    float* __restrict__ u, float* __restrict__ v, int nrows)
{
    __shared__ float lx[BT * 64];
    const int row0 = blockIdx.x * BT;
    const int nr = min(BT, nrows - row0);
    stage_rows<64>(n + (long long)row0 * 64, nr, lx);
    __syncthreads();
    const int row = threadIdx.x;
    if (row >= nr) return;
    float acc[64];
    #pragma unroll
    for (int j = 0; j < 64; ++j) acc[j] = 0.f;
    accum<64>(lx, row, Wb, acc);
    store_row64(u + (long long)(row0 + row) * 64, acc);
    #pragma unroll
    for (int j = 0; j < 64; ++j) acc[j] = 0.f;
    accum<64>(lx, row, Wc, acc);
    store_row64(v + (long long)(row0 + row) * 64, acc);
}

// ------- edge update: e += MLP(e@A + u[s] + v[r] + b1); scatter-add into aggr[s] -------
__global__ __launch_bounds__(BT, 2) void k_edge(
    float* __restrict__ e, const int* __restrict__ eidx,
    const float* __restrict__ u, const float* __restrict__ v,
    const float* __restrict__ A, const float* __restrict__ b1,
    const float* __restrict__ W2, const float* __restrict__ b2,
    const float* __restrict__ g, const float* __restrict__ be,
    float* __restrict__ aggr, int nrows)
{
    __shared__ float lx[BT * 64];
    const int row0 = blockIdx.x * BT;
    const int nr = min(BT, nrows - row0);
    stage_rows<64>(e + (long long)row0 * 64, nr, lx);
    __syncthreads();
    const int row = threadIdx.x;
    if (row >= nr) return;
    const int grow = row0 + row;
    const int s = eidx[2 * grow], r = eidx[2 * grow + 1];
    const float4* us = reinterpret_cast<const float4*>(u + (long long)s * 64);
    const float4* vp = reinterpret_cast<const float4*>(v + (long long)r * 64);
    float acc[64];
    #pragma unroll
    for (int q = 0; q < 16; ++q) {
        const float4 a4 = us[q], c4 = vp[q];
        acc[4*q+0] = b1[4*q+0] + a4.x + c4.x;
        acc[4*q+1] = b1[4*q+1] + a4.y + c4.y;
        acc[4*q+2] = b1[4*q+2] + a4.z + c4.z;
        acc[4*q+3] = b1[4*q+3] + a4.w + c4.w;
    }
    accum<64>(lx, row, A, acc);
    const int base = row << 6, m = row & 31;
    float eold[64];
    #pragma unroll
    for (int k = 0; k < 64; ++k) eold[k] = lx[base + (k ^ m)];
    #pragma unroll
    for (int k = 0; k < 64; ++k) lx[base + (k ^ m)] = lrelu(acc[k]);
    #pragma unroll
    for (int j = 0; j < 64; ++j) acc[j] = b2[j];
    accum<64>(lx, row, W2, acc);
    #pragma unroll
    for (int j = 0; j < 64; ++j) acc[j] = lrelu(acc[j]);
    layernorm(acc, g, be);
    #pragma unroll
    for (int j = 0; j < 64; ++j) acc[j] += eold[j];
    store_row64(e + (long long)grow * 64, acc);
    float* ar = aggr + (long long)s * 64;
    #pragma unroll
    for (int j = 0; j < 64; ++j) atomicAdd(ar + j, acc[j]);
}

// ------- node update: n += MLP(concat[n, aggr]); W1 is 128x64 (two 64x64 halves) -------
__global__ __launch_bounds__(BT, 2) void k_node(
    float* __restrict__ n, const float* __restrict__ aggr,
    const float* __restrict__ W1, const float* __restrict__ b1,
    const float* __restrict__ W2, const float* __restrict__ b2,
    const float* __restrict__ g, const float* __restrict__ be, int nrows)
{
    __shared__ float lx[BT * 64];
    const int row0 = blockIdx.x * BT;
    const int nr = min(BT, nrows - row0);
    const int row = threadIdx.x;
    float acc[64], nold[64];
    stage_rows<64>(n + (long long)row0 * 64, nr, lx);
    __syncthreads();
    if (row < nr) {
        #pragma unroll
        for (int j = 0; j < 64; ++j) acc[j] = b1[j];
        accum<64>(lx, row, W1, acc);
        const int base = row << 6, m = row & 31;
        #pragma unroll
        for (int k = 0; k < 64; ++k) nold[k] = lx[base + (k ^ m)];
    }
    __syncthreads();                      // everyone done reading n-tile
    stage_rows<64>(aggr + (long long)row0 * 64, nr, lx);
    __syncthreads();
    if (row < nr) {
        accum<64>(lx, row, W1 + 64 * 64, acc);
        const int base = row << 6, m = row & 31;
        #pragma unroll
        for (int k = 0; k < 64; ++k) lx[base + (k ^ m)] = lrelu(acc[k]);
        #pragma unroll
        for (int j = 0; j < 64; ++j) acc[j] = b2[j];
        accum<64>(lx, row, W2, acc);
        #pragma unroll
        for (int j = 0; j < 64; ++j) acc[j] = lrelu(acc[j]);
        layernorm(acc, g, be);
        #pragma unroll
        for (int j = 0; j < 64; ++j) acc[j] += nold[j];
        store_row64(n + (long long)(row0 + row) * 64, acc);
    }
}

// ---------------- decoder: out = lrelu(n@W1+b1) @ W2 + b2, OUT=3 ----------------
__global__ __launch_bounds__(BT, 2) void k_dec(
    const float* __restrict__ n, const float* __restrict__ W1, const float* __restrict__ b1,
    const float* __restrict__ W2, const float* __restrict__ b2,
    float* __restrict__ out, int nrows)
{
    __shared__ float lx[BT * 64];
    const int row0 = blockIdx.x * BT;
    const int nr = min(BT, nrows - row0);
    stage_rows<64>(n + (long long)row0 * 64, nr, lx);
    __syncthreads();
    const int row = threadIdx.x;
    if (row >= nr) return;
    float acc[64];
    #pragma unroll
    for (int j = 0; j < 64; ++j) acc[j] = b1[j];
    accum<64>(lx, row, W1, acc);
    const int base = row << 6, m = row & 31;
    #pragma unroll
    for (int k = 0; k < 64; ++k) lx[base + (k ^ m)] = lrelu(acc[k]);
    float o0 = b2[0], o1 = b2[1], o2 = b2[2];
    #pragma unroll 4
    for (int k = 0; k < 64; ++k) {
        const float h = lx[base + (k ^ m)];
        o0 = fmaf(h, W2[k * 3 + 0], o0);
        o1 = fmaf(h, W2[k * 3 + 1], o1);
        o2 = fmaf(h, W2[k * 3 + 2], o2);
    }
    float* op = out + (long long)(row0 + row) * 3;
    op[0] = o0; op[1] = o1; op[2] = o2;
}

extern "C" void kernel_launch(void* const* d_in, const int* in_sizes, int n_in,
                              void* d_out, int out_size, void* d_ws, size_t ws_size,
                              hipStream_t stream)
{
    (void)in_sizes; (void)n_in; (void)out_size; (void)ws_size;
    constexpr int N = 50000, E = 300000, L = 3;

    const float* nodes = (const float*)d_in[0];
    const float* edges = (const float*)d_in[1];
    const int*   eidx  = (const int*)d_in[2];
    const float* neW1 = (const float*)d_in[3];
    const float* neb1 = (const float*)d_in[4];
    const float* neW2 = (const float*)d_in[5];
    const float* neb2 = (const float*)d_in[6];
    const float* neg  = (const float*)d_in[7];
    const float* nebe = (const float*)d_in[8];
    const float* eeW1 = (const float*)d_in[9];
    const float* eeb1 = (const float*)d_in[10];
    const float* eeW2 = (const float*)d_in[11];
    const float* eeb2 = (const float*)d_in[12];
    const float* eeg  = (const float*)d_in[13];
    const float* eebe = (const float*)d_in[14];
    const float* nmW1 = (const float*)d_in[15];
    const float* nmb1 = (const float*)d_in[16];
    const float* nmW2 = (const float*)d_in[17];
    const float* nmb2 = (const float*)d_in[18];
    const float* nmg  = (const float*)d_in[19];
    const float* nmbe = (const float*)d_in[20];
    const float* emW1 = (const float*)d_in[21];
    const float* emb1 = (const float*)d_in[22];
    const float* emW2 = (const float*)d_in[23];
    const float* emb2 = (const float*)d_in[24];
    const float* emg  = (const float*)d_in[25];
    const float* embe = (const float*)d_in[26];
    const float* decW1 = (const float*)d_in[27];
    const float* decb1 = (const float*)d_in[28];
    const float* decW2 = (const float*)d_in[29];
    const float* decb2 = (const float*)d_in[30];

    float* n    = (float*)d_ws;                 // N*64
    float* u    = n    + (size_t)N * 64;        // N*64
    float* v    = u    + (size_t)N * 64;        // N*64
    float* aggr = v    + (size_t)N * 64;        // N*64
    float* e    = aggr + (size_t)N * 64;        // E*64

    const int nbN = (N + BT - 1) / BT;
    const int nbE = (E + BT - 1) / BT;

    k_encode<16><<<nbN, BT, 0, stream>>>(nodes, neW1, neb1, neW2, neb2, neg, nebe, n, N);
    k_encode<8> <<<nbE, BT, 0, stream>>>(edges, eeW1, eeb1, eeW2, eeb2, eeg, eebe, e, E);

    for (int i = 0; i < L; ++i) {
        const float* A = emW1 + (size_t)i * 192 * 64;
        k_uv<<<nbN, BT, 0, stream>>>(n, A + 64 * 64, A + 128 * 64, u, v, N);
        hipMemsetAsync(aggr, 0, (size_t)N * 64 * sizeof(float), stream);
        k_edge<<<nbE, BT, 0, stream>>>(e, eidx, u, v, A,
                                       emb1 + i * 64, emW2 + (size_t)i * 64 * 64,
                                       emb2 + i * 64, emg + i * 64, embe + i * 64, aggr, E);
        k_node<<<nbN, BT, 0, stream>>>(n, aggr, nmW1 + (size_t)i * 128 * 64, nmb1 + i * 64,
                                       nmW2 + (size_t)i * 64 * 64, nmb2 + i * 64,
                                       nmg + i * 64, nmbe + i * 64, N);
    }
    k_dec<<<nbN, BT, 0, stream>>>(n, decW1, decb1, decW2, decb2, (float*)d_out, N);
}

// Round 2
// 1306.061 us; speedup vs baseline: 3.0248x; 3.0248x over previous
//
#include <hip/hip_runtime.h>

constexpr int BT = 256;   // threads per block == rows per block

__device__ __forceinline__ float lrelu(float x) { return x >= 0.f ? x : 0.05f * x; }

// Coalesced global->LDS staging of nr rows of DIN floats (DIN % 4 == 0).
// Word index XOR-swizzled by (row&31): per-k reads are 2-way bank pattern = free.
template<int DIN>
__device__ __forceinline__ void stage_rows(const float* __restrict__ g, int nr, float* __restrict__ lx)
{
    const int total = nr * DIN;
    for (int idx = threadIdx.x * 4; idx < total; idx += BT * 4) {
        const float4 vv = *reinterpret_cast<const float4*>(g + idx);
        const int row = idx / DIN;
        const int k = idx - row * DIN;
        const int m = row & 31, p = m & 3;
        const float e0 = (p & 2) ? vv.z : vv.x;
        const float e1 = (p & 2) ? vv.w : vv.y;
        const float e2 = (p & 2) ? vv.x : vv.z;
        const float e3 = (p & 2) ? vv.y : vv.w;
        const float f0 = (p & 1) ? e1 : e0;
        const float f1 = (p & 1) ? e0 : e1;
        const float f2 = (p & 1) ? e3 : e2;
        const float f3 = (p & 1) ? e2 : e3;
        const int q = (row << 6) + ((k ^ m) & ~3);
        *reinterpret_cast<float4*>(lx + q) = make_float4(f0, f1, f2, f3);
    }
}

// acc[j] += sum_k x[row][k] * W[k*64+j].  W accesses are wave-uniform.
template<int DIN>
__device__ __forceinline__ void accum(const float* __restrict__ lx, int row,
                                      const float* __restrict__ W, float* __restrict__ acc)
{
    const int base = row << 6, m = row & 31;
    #pragma unroll 4
    for (int k = 0; k < DIN; ++k) {
        const float xv = lx[base + (k ^ m)];
        const float* wr = W + k * 64;
        #pragma unroll
        for (int j = 0; j < 64; ++j)
            acc[j] = fmaf(xv, wr[j], acc[j]);
    }
}

__device__ __forceinline__ void layernorm(float* __restrict__ a,
                                          const float* __restrict__ g, const float* __restrict__ be)
{
    float mu = 0.f;
    #pragma unroll
    for (int j = 0; j < 64; ++j) mu += a[j];
    mu *= 0.015625f;
    float var = 0.f;
    #pragma unroll
    for (int j = 0; j < 64; ++j) { const float d = a[j] - mu; var = fmaf(d, d, var); }
    var *= 0.015625f;
    const float rs = rsqrtf(var + 1e-5f);
    #pragma unroll
    for (int j = 0; j < 64; ++j) a[j] = (a[j] - mu) * rs * g[j] + be[j];
}

__device__ __forceinline__ void store_row64(float* __restrict__ dst, const float* __restrict__ a)
{
    #pragma unroll
    for (int q = 0; q < 16; ++q)
        reinterpret_cast<float4*>(dst)[q] = make_float4(a[4*q], a[4*q+1], a[4*q+2], a[4*q+3]);
}

// ---------------- encoder (2-layer MLP + LN), DIN in {16, 8} ----------------
template<int DIN>
__global__ __launch_bounds__(BT, 2) void k_encode(
    const float* __restrict__ x,
    const float* __restrict__ W1, const float* __restrict__ b1,
    const float* __restrict__ W2, const float* __restrict__ b2,
    const float* __restrict__ g, const float* __restrict__ be,
    float* __restrict__ out, int nrows)
{
    __shared__ float lx[BT * 64];
    const int row0 = blockIdx.x * BT;
    const int nr = min(BT, nrows - row0);
    stage_rows<DIN>(x + (long long)row0 * DIN, nr, lx);
    __syncthreads();
    const int row = threadIdx.x;
    if (row >= nr) return;
    float acc[64];
    #pragma unroll
    for (int j = 0; j < 64; ++j) acc[j] = b1[j];
    accum<DIN>(lx, row, W1, acc);
    const int base = row << 6, m = row & 31;
    #pragma unroll
    for (int k = 0; k < 64; ++k) lx[base + (k ^ m)] = lrelu(acc[k]);
    #pragma unroll
    for (int j = 0; j < 64; ++j) acc[j] = b2[j];
    accum<64>(lx, row, W2, acc);
    #pragma unroll
    for (int j = 0; j < 64; ++j) acc[j] = lrelu(acc[j]);
    layernorm(acc, g, be);
    store_row64(out + (long long)(row0 + row) * 64, acc);
}

// ---------------- u = n@B, v = n@C (edge-MLP W1 partial products) ----------------
__global__ __launch_bounds__(BT, 2) void k_uv(
    const float* __restrict__ n, const float* __restrict__ Wb, const float* __restrict__ Wc,
    float* __restrict__ u, float* __restrict__ v, int nrows)
{
    __shared__ float lx[BT * 64];
    const int row0 = blockIdx.x * BT;
    const int nr = min(BT, nrows - row0);
    stage_rows<64>(n + (long long)row0 * 64, nr, lx);
    __syncthreads();
    const int row = threadIdx.x;
    if (row >= nr) return;
    float acc[64];
    #pragma unroll
    for (int j = 0; j < 64; ++j) acc[j] = 0.f;
    accum<64>(lx, row, Wb, acc);
    store_row64(u + (long long)(row0 + row) * 64, acc);
    #pragma unroll
    for (int j = 0; j < 64; ++j) acc[j] = 0.f;
    accum<64>(lx, row, Wc, acc);
    store_row64(v + (long long)(row0 + row) * 64, acc);
}

// ------- edge update: e += MLP(e@A + u[s] + v[r] + b1)  (no atomics) -------
__global__ __launch_bounds__(BT, 2) void k_edge(
    float* __restrict__ e, const int* __restrict__ eidx,
    const float* __restrict__ u, const float* __restrict__ v,
    const float* __restrict__ A, const float* __restrict__ b1,
    const float* __restrict__ W2, const float* __restrict__ b2,
    const float* __restrict__ g, const float* __restrict__ be,
    int nrows)
{
    __shared__ float lx[BT * 64];
    const int row0 = blockIdx.x * BT;
    const int nr = min(BT, nrows - row0);
    stage_rows<64>(e + (long long)row0 * 64, nr, lx);
    __syncthreads();
    const int row = threadIdx.x;
    if (row >= nr) return;
    const int grow = row0 + row;
    const int s = eidx[2 * grow], r = eidx[2 * grow + 1];
    const float4* us = reinterpret_cast<const float4*>(u + (long long)s * 64);
    const float4* vp = reinterpret_cast<const float4*>(v + (long long)r * 64);
    float acc[64];
    #pragma unroll
    for (int q = 0; q < 16; ++q) {
        const float4 a4 = us[q], c4 = vp[q];
        acc[4*q+0] = b1[4*q+0] + a4.x + c4.x;
        acc[4*q+1] = b1[4*q+1] + a4.y + c4.y;
        acc[4*q+2] = b1[4*q+2] + a4.z + c4.z;
        acc[4*q+3] = b1[4*q+3] + a4.w + c4.w;
    }
    accum<64>(lx, row, A, acc);
    const int base = row << 6, m = row & 31;
    float eold[64];
    #pragma unroll
    for (int k = 0; k < 64; ++k) eold[k] = lx[base + (k ^ m)];
    #pragma unroll
    for (int k = 0; k < 64; ++k) lx[base + (k ^ m)] = lrelu(acc[k]);
    #pragma unroll
    for (int j = 0; j < 64; ++j) acc[j] = b2[j];
    accum<64>(lx, row, W2, acc);
    #pragma unroll
    for (int j = 0; j < 64; ++j) acc[j] = lrelu(acc[j]);
    layernorm(acc, g, be);
    #pragma unroll
    for (int j = 0; j < 64; ++j) acc[j] += eold[j];
    store_row64(e + (long long)grow * 64, acc);
}

// ------- CSR build: histogram, block scan, scatter -------
__global__ void k_hist(const int* __restrict__ eidx, int* __restrict__ cnt, int E)
{
    int i = blockIdx.x * 256 + threadIdx.x;
    if (i < E) atomicAdd(&cnt[eidx[2 * i]], 1);
}

__global__ void k_scan1(const int* __restrict__ cnt, int* __restrict__ starts,
                        int* __restrict__ bsum, int n)
{
    __shared__ int sh[256];
    const int tid = threadIdx.x;
    const int i = blockIdx.x * 256 + tid;
    const int val = (i < n) ? cnt[i] : 0;
    sh[tid] = val; __syncthreads();
    for (int off = 1; off < 256; off <<= 1) {
        int t = (tid >= off) ? sh[tid - off] : 0;
        __syncthreads();
        sh[tid] += t;
        __syncthreads();
    }
    if (i < n) starts[i] = sh[tid] - val;         // exclusive within block
    if (tid == 255) bsum[blockIdx.x] = sh[255];   // block total
}

__global__ void k_scan2(int* __restrict__ bsum, int nb)   // single block, nb<=256
{
    __shared__ int sh[256];
    const int tid = threadIdx.x;
    const int val = (tid < nb) ? bsum[tid] : 0;
    sh[tid] = val; __syncthreads();
    for (int off = 1; off < 256; off <<= 1) {
        int t = (tid >= off) ? sh[tid - off] : 0;
        __syncthreads();
        sh[tid] += t;
        __syncthreads();
    }
    if (tid < nb) bsum[tid] = sh[tid] - val;      // exclusive block offsets
}

__global__ void k_scan3(int* __restrict__ starts, const int* __restrict__ bsum, int n)
{
    int i = blockIdx.x * 256 + threadIdx.x;
    if (i < n) starts[i] += bsum[blockIdx.x];
}

__global__ void k_scatter(const int* __restrict__ eidx, const int* __restrict__ starts,
                          int* __restrict__ cursor, int* __restrict__ csr, int E)
{
    int i = blockIdx.x * 256 + threadIdx.x;
    if (i < E) {
        const int s = eidx[2 * i];
        const int p = atomicAdd(&cursor[s], 1);
        csr[starts[s] + p] = i;
    }
}

// ------- aggregation: one wave per node, lane = column; deterministic-set gather -------
__global__ __launch_bounds__(256) void k_aggr(
    const float* __restrict__ e, const int* __restrict__ starts, const int* __restrict__ cnt,
    const int* __restrict__ csr, float* __restrict__ aggr, int N)
{
    const int node = blockIdx.x * 4 + (threadIdx.x >> 6);
    if (node >= N) return;
    const int j = threadIdx.x & 63;
    const int st = starts[node], en = st + cnt[node];
    float a = 0.f;
    for (int t = st; t < en; ++t) {
        const int eid = csr[t];
        a += e[(long long)eid * 64 + j];
    }
    aggr[(long long)node * 64 + j] = a;
}

// ------- node update: n += MLP(concat[n, aggr]) -------
__global__ __launch_bounds__(BT, 2) void k_node(
    float* __restrict__ n, const float* __restrict__ aggr,
    const float* __restrict__ W1, const float* __restrict__ b1,
    const float* __restrict__ W2, const float* __restrict__ b2,
    const float* __restrict__ g, const float* __restrict__ be, int nrows)
{
    __shared__ float lx[BT * 64];
    const int row0 = blockIdx.x * BT;
    const int nr = min(BT, nrows - row0);
    const int row = threadIdx.x;
    float acc[64], nold[64];
    stage_rows<64>(n + (long long)row0 * 64, nr, lx);
    __syncthreads();
    if (row < nr) {
        #pragma unroll
        for (int j = 0; j < 64; ++j) acc[j] = b1[j];
        accum<64>(lx, row, W1, acc);
        const int base = row << 6, m = row & 31;
        #pragma unroll
        for (int k = 0; k < 64; ++k) nold[k] = lx[base + (k ^ m)];
    }
    __syncthreads();
    stage_rows<64>(aggr + (long long)row0 * 64, nr, lx);
    __syncthreads();
    if (row < nr) {
        accum<64>(lx, row, W1 + 64 * 64, acc);
        const int base = row << 6, m = row & 31;
        #pragma unroll
        for (int k = 0; k < 64; ++k) lx[base + (k ^ m)] = lrelu(acc[k]);
        #pragma unroll
        for (int j = 0; j < 64; ++j) acc[j] = b2[j];
        accum<64>(lx, row, W2, acc);
        #pragma unroll
        for (int j = 0; j < 64; ++j) acc[j] = lrelu(acc[j]);
        layernorm(acc, g, be);
        #pragma unroll
        for (int j = 0; j < 64; ++j) acc[j] += nold[j];
        store_row64(n + (long long)(row0 + row) * 64, acc);
    }
}

// ---------------- decoder ----------------
__global__ __launch_bounds__(BT, 2) void k_dec(
    const float* __restrict__ n, const float* __restrict__ W1, const float* __restrict__ b1,
    const float* __restrict__ W2, const float* __restrict__ b2,
    float* __restrict__ out, int nrows)
{
    __shared__ float lx[BT * 64];
    const int row0 = blockIdx.x * BT;
    const int nr = min(BT, nrows - row0);
    stage_rows<64>(n + (long long)row0 * 64, nr, lx);
    __syncthreads();
    const int row = threadIdx.x;
    if (row >= nr) return;
    float acc[64];
    #pragma unroll
    for (int j = 0; j < 64; ++j) acc[j] = b1[j];
    accum<64>(lx, row, W1, acc);
    const int base = row << 6, m = row & 31;
    #pragma unroll
    for (int k = 0; k < 64; ++k) lx[base + (k ^ m)] = lrelu(acc[k]);
    float o0 = b2[0], o1 = b2[1], o2 = b2[2];
    #pragma unroll 4
    for (int k = 0; k < 64; ++k) {
        const float h = lx[base + (k ^ m)];
        o0 = fmaf(h, W2[k * 3 + 0], o0);
        o1 = fmaf(h, W2[k * 3 + 1], o1);
        o2 = fmaf(h, W2[k * 3 + 2], o2);
    }
    float* op = out + (long long)(row0 + row) * 3;
    op[0] = o0; op[1] = o1; op[2] = o2;
}

extern "C" void kernel_launch(void* const* d_in, const int* in_sizes, int n_in,
                              void* d_out, int out_size, void* d_ws, size_t ws_size,
                              hipStream_t stream)
{
    (void)in_sizes; (void)n_in; (void)out_size; (void)ws_size;
    constexpr int N = 50000, E = 300000, L = 3;

    const float* nodes = (const float*)d_in[0];
    const float* edges = (const float*)d_in[1];
    const int*   eidx  = (const int*)d_in[2];
    const float* neW1 = (const float*)d_in[3];
    const float* neb1 = (const float*)d_in[4];
    const float* neW2 = (const float*)d_in[5];
    const float* neb2 = (const float*)d_in[6];
    const float* neg  = (const float*)d_in[7];
    const float* nebe = (const float*)d_in[8];
    const float* eeW1 = (const float*)d_in[9];
    const float* eeb1 = (const float*)d_in[10];
    const float* eeW2 = (const float*)d_in[11];
    const float* eeb2 = (const float*)d_in[12];
    const float* eeg  = (const float*)d_in[13];
    const float* eebe = (const float*)d_in[14];
    const float* nmW1 = (const float*)d_in[15];
    const float* nmb1 = (const float*)d_in[16];
    const float* nmW2 = (const float*)d_in[17];
    const float* nmb2 = (const float*)d_in[18];
    const float* nmg  = (const float*)d_in[19];
    const float* nmbe = (const float*)d_in[20];
    const float* emW1 = (const float*)d_in[21];
    const float* emb1 = (const float*)d_in[22];
    const float* emW2 = (const float*)d_in[23];
    const float* emb2 = (const float*)d_in[24];
    const float* emg  = (const float*)d_in[25];
    const float* embe = (const float*)d_in[26];
    const float* decW1 = (const float*)d_in[27];
    const float* decb1 = (const float*)d_in[28];
    const float* decW2 = (const float*)d_in[29];
    const float* decb2 = (const float*)d_in[30];

    // workspace layout (floats):  n | u(=aggr) | v | e | ints...
    float* n   = (float*)d_ws;                  // N*64
    float* u   = n + (size_t)N * 64;            // N*64  (reused as aggr)
    float* v   = u + (size_t)N * 64;            // N*64
    float* e   = v + (size_t)N * 64;            // E*64
    int* cnt    = (int*)(e + (size_t)E * 64);   // N
    int* starts = cnt + N;                      // N
    int* csr    = starts + N;                   // E
    int* bsum   = csr + E;                      // 256
    int* cursor = bsum + 256;                   // N

    const int nbN = (N + BT - 1) / BT;          // 196
    const int nbE = (E + BT - 1) / BT;          // 1172

    // ---- CSR build (once per launch; reused for all 3 layers) ----
    hipMemsetAsync(cnt, 0, (size_t)N * sizeof(int), stream);
    hipMemsetAsync(cursor, 0, (size_t)N * sizeof(int), stream);
    k_hist<<<nbE, 256, 0, stream>>>(eidx, cnt, E);
    k_scan1<<<nbN, 256, 0, stream>>>(cnt, starts, bsum, N);
    k_scan2<<<1, 256, 0, stream>>>(bsum, nbN);
    k_scan3<<<nbN, 256, 0, stream>>>(starts, bsum, N);
    k_scatter<<<nbE, 256, 0, stream>>>(eidx, starts, cursor, csr, E);

    // ---- encode ----
    k_encode<16><<<nbN, BT, 0, stream>>>(nodes, neW1, neb1, neW2, neb2, neg, nebe, n, N);
    k_encode<8> <<<nbE, BT, 0, stream>>>(edges, eeW1, eeb1, eeW2, eeb2, eeg, eebe, e, E);

    // ---- message-passing layers ----
    for (int i = 0; i < L; ++i) {
        const float* A = emW1 + (size_t)i * 192 * 64;
        k_uv<<<nbN, BT, 0, stream>>>(n, A + 64 * 64, A + 128 * 64, u, v, N);
        k_edge<<<nbE, BT, 0, stream>>>(e, eidx, u, v, A,
                                       emb1 + i * 64, emW2 + (size_t)i * 64 * 64,
                                       emb2 + i * 64, emg + i * 64, embe + i * 64, E);
        k_aggr<<<(N + 3) / 4, 256, 0, stream>>>(e, starts, cnt, csr, u, N);  // u := aggr
        k_node<<<nbN, BT, 0, stream>>>(n, u, nmW1 + (size_t)i * 128 * 64, nmb1 + i * 64,
                                       nmW2 + (size_t)i * 64 * 64, nmb2 + i * 64,
                                       nmg + i * 64, nmbe + i * 64, N);
    }
    k_dec<<<nbN, BT, 0, stream>>>(n, decW1, decb1, decW2, decb2, (float*)d_out, N);
}

// Round 3
// 593.818 us; speedup vs baseline: 6.6529x; 2.1994x over previous
//
#include <hip/hip_runtime.h>

constexpr int BT = 256;

typedef __attribute__((ext_vector_type(8))) short short8v;
typedef __attribute__((ext_vector_type(4))) short short4v;
typedef __attribute__((ext_vector_type(4))) float f32x4;

__device__ __forceinline__ float lrelu(float x) { return x >= 0.f ? x : 0.05f * x; }

__device__ __forceinline__ unsigned short bf16_rne(float x) {
    unsigned u = __float_as_uint(x);
    u += 0x7FFFu + ((u >> 16) & 1u);
    return (unsigned short)(u >> 16);
}
__device__ __forceinline__ float bf16_to_f(unsigned short h) {
    return __uint_as_float(((unsigned)h) << 16);
}
__device__ __forceinline__ void split2(float x, unsigned short& hi, unsigned short& lo) {
    hi = bf16_rne(x);
    lo = bf16_rne(x - bf16_to_f(hi));
}

// ================= MFMA machinery =================
// A-frag (M=16,K=32): lane holds A[row=lane&15][k=(lane>>4)*8+i], i=0..7
// B-frag: lane holds B[k=(lane>>4)*8+i][col=lane&15]
// C/D: col=lane&15, row=(lane>>4)*4+reg   [m89-verified]
// LDS A layout per plane: A[row][k] shorts, 16B slots XOR-swizzled: slot = (k>>3)^(row&7)

// stage 64 rows x 64 cols fp32 -> hi/lo bf16 LDS planes (A and A+4096)
__device__ __forceinline__ void stageA64(const float* __restrict__ src, int row0, int nrows,
                                         short* __restrict__ A)
{
    for (int q = threadIdx.x; q < 1024; q += 256) {
        const int row = q >> 4;
        const int k0 = (q & 15) << 2;
        const int grow = row0 + row;
        float4 x = (grow < nrows) ? *reinterpret_cast<const float4*>(src + (long long)grow * 64 + k0)
                                  : make_float4(0.f, 0.f, 0.f, 0.f);
        unsigned short h0,h1,h2,h3,l0,l1,l2,l3;
        split2(x.x, h0, l0); split2(x.y, h1, l1); split2(x.z, h2, l2); split2(x.w, h3, l3);
        const int off = row * 64 + ((((k0 >> 3) ^ (row & 7))) << 3) + (k0 & 7);
        short4v hv; hv[0]=(short)h0; hv[1]=(short)h1; hv[2]=(short)h2; hv[3]=(short)h3;
        short4v lv; lv[0]=(short)l0; lv[1]=(short)l1; lv[2]=(short)l2; lv[3]=(short)l3;
        *reinterpret_cast<short4v*>(A + off) = hv;
        *reinterpret_cast<short4v*>(A + 4096 + off) = lv;
    }
}

// acc[t] += X[16 rows][64] @ W[64][64] (split-bf16, 3-term), A = LDS hi plane (lo at +4096),
// wf = preformatted global B-fragments: ((s*4+t)*2+p)*512 + lane*8
__device__ __forceinline__ void gemm64(const short* __restrict__ A, const short* __restrict__ wf,
                                       int row, int g, int lane, f32x4* __restrict__ acc)
{
    #pragma unroll
    for (int s = 0; s < 2; ++s) {
        const int k8 = s * 4 + g;
        const int aoff = row * 64 + ((k8 ^ (row & 7)) << 3);
        const short8v a_hi = *reinterpret_cast<const short8v*>(A + aoff);
        const short8v a_lo = *reinterpret_cast<const short8v*>(A + 4096 + aoff);
        #pragma unroll
        for (int t = 0; t < 4; ++t) {
            const short8v b_hi = *reinterpret_cast<const short8v*>(wf + ((s*4+t)*2+0)*512 + lane*8);
            const short8v b_lo = *reinterpret_cast<const short8v*>(wf + ((s*4+t)*2+1)*512 + lane*8);
            acc[t] = __builtin_amdgcn_mfma_f32_16x16x32_bf16(a_hi, b_hi, acc[t], 0, 0, 0);
            acc[t] = __builtin_amdgcn_mfma_f32_16x16x32_bf16(a_lo, b_hi, acc[t], 0, 0, 0);
            acc[t] = __builtin_amdgcn_mfma_f32_16x16x32_bf16(a_hi, b_lo, acc[t], 0, 0, 0);
        }
    }
}

// Preformat 64x64 fp32 W[k][col] chunks -> hi/lo B-fragments.
// chunk cid: layer = cid/7, j = cid%7: [A,B,C,W2e,W1a,W1b,W2n]
__global__ void k_prepw(const float* __restrict__ emW1, const float* __restrict__ emW2,
                        const float* __restrict__ nmW1, const float* __restrict__ nmW2,
                        short* __restrict__ wf)
{
    const int cid = blockIdx.x;
    const int layer = cid / 7, j = cid % 7;
    const float* src =
        j == 0 ? emW1 + (size_t)layer * 12288 :
        j == 1 ? emW1 + (size_t)layer * 12288 + 4096 :
        j == 2 ? emW1 + (size_t)layer * 12288 + 8192 :
        j == 3 ? emW2 + (size_t)layer * 4096 :
        j == 4 ? nmW1 + (size_t)layer * 8192 :
        j == 5 ? nmW1 + (size_t)layer * 8192 + 4096 :
                 nmW2 + (size_t)layer * 4096;
    short* dst = wf + (size_t)cid * 8192;
    for (int fr = threadIdx.x; fr < 1024; fr += 256) {
        const int lane = fr & 63;
        const int stp = fr >> 6;
        const int p = stp & 1;
        const int st = stp >> 1;
        const int s = st >> 2, t = st & 3;
        const int col = t * 16 + (lane & 15);
        const int k0 = s * 32 + (lane >> 4) * 8;
        short8v o;
        #pragma unroll
        for (int i = 0; i < 8; ++i) {
            const float w = src[(k0 + i) * 64 + col];
            const unsigned short hi = bf16_rne(w);
            o[i] = (short)(p ? bf16_rne(w - bf16_to_f(hi)) : hi);
        }
        *reinterpret_cast<short8v*>(dst + fr * 8) = o;
    }
}

// ---------------- u = n@B, v = n@C ----------------
__global__ __launch_bounds__(256) void k_uv_mf(
    const float* __restrict__ n, const short* __restrict__ wfB, const short* __restrict__ wfC,
    float* __restrict__ u, float* __restrict__ v, int N)
{
    __shared__ short Ab[8192];
    const int row0 = blockIdx.x * 64;
    stageA64(n, row0, N, Ab);
    __syncthreads();
    const int lane = threadIdx.x & 63;
    const int wm = threadIdx.x >> 6;
    const int g = lane >> 4, c = lane & 15;
    const int rowA = wm * 16 + c;
    const f32x4 z4 = {0.f, 0.f, 0.f, 0.f};
    f32x4 acc[4];
    #pragma unroll
    for (int t = 0; t < 4; ++t) acc[t] = z4;
    gemm64(Ab, wfB, rowA, g, lane, acc);
    #pragma unroll
    for (int r = 0; r < 4; ++r) {
        const int grow = row0 + wm * 16 + g * 4 + r;
        if (grow < N) {
            #pragma unroll
            for (int t = 0; t < 4; ++t) u[(long long)grow * 64 + t * 16 + c] = acc[t][r];
        }
    }
    #pragma unroll
    for (int t = 0; t < 4; ++t) acc[t] = z4;
    gemm64(Ab, wfC, rowA, g, lane, acc);
    #pragma unroll
    for (int r = 0; r < 4; ++r) {
        const int grow = row0 + wm * 16 + g * 4 + r;
        if (grow < N) {
            #pragma unroll
            for (int t = 0; t < 4; ++t) v[(long long)grow * 64 + t * 16 + c] = acc[t][r];
        }
    }
}

// ---------------- edge update: e += LN(lrelu(lrelu(e@A + u[s] + v[r] + b1)@W2 + b2)) ----------------
__global__ __launch_bounds__(256) void k_edge_mf(
    float* __restrict__ e, const int* __restrict__ eidx,
    const float* __restrict__ u, const float* __restrict__ v,
    const short* __restrict__ wfA, const short* __restrict__ wfW2,
    const float* __restrict__ b1, const float* __restrict__ b2,
    const float* __restrict__ gam, const float* __restrict__ bet, int E)
{
    __shared__ short Ab[8192];
    __shared__ short Hf[8192];
    const int row0 = blockIdx.x * 64;
    stageA64(e, row0, E, Ab);
    __syncthreads();
    const int lane = threadIdx.x & 63;
    const int wm = threadIdx.x >> 6;
    const int g = lane >> 4, c = lane & 15;
    const int rowA = wm * 16 + c;
    int sidx[4], ridx[4];
    #pragma unroll
    for (int r = 0; r < 4; ++r) {
        const int grow = row0 + wm * 16 + g * 4 + r;
        if (grow < E) { sidx[r] = eidx[2 * grow]; ridx[r] = eidx[2 * grow + 1]; }
        else          { sidx[r] = 0; ridx[r] = 0; }
    }
    const f32x4 z4 = {0.f, 0.f, 0.f, 0.f};
    f32x4 acc[4];
    #pragma unroll
    for (int t = 0; t < 4; ++t) acc[t] = z4;
    gemm64(Ab, wfA, rowA, g, lane, acc);
    #pragma unroll
    for (int t = 0; t < 4; ++t) {
        const int col = t * 16 + c;
        const float b1v = b1[col];
        #pragma unroll
        for (int r = 0; r < 4; ++r)
            acc[t][r] += b1v + u[(long long)sidx[r] * 64 + col] + v[(long long)ridx[r] * 64 + col];
    }
    // lrelu -> split -> Hf (A-frag layout for GEMM2); own wave's rows only, no barrier needed
    #pragma unroll
    for (int t = 0; t < 4; ++t) {
        const int col = t * 16 + c;
        #pragma unroll
        for (int r = 0; r < 4; ++r) {
            const int rl = wm * 16 + g * 4 + r;
            const float h = lrelu(acc[t][r]);
            unsigned short hi, lo; split2(h, hi, lo);
            const int off = rl * 64 + (((col >> 3) ^ (rl & 7)) << 3) + (col & 7);
            Hf[off] = (short)hi;
            Hf[4096 + off] = (short)lo;
        }
    }
    f32x4 acc2[4];
    #pragma unroll
    for (int t = 0; t < 4; ++t) acc2[t] = z4;
    gemm64(Hf, wfW2, rowA, g, lane, acc2);
    #pragma unroll
    for (int t = 0; t < 4; ++t) {
        const float b2v = b2[t * 16 + c];
        #pragma unroll
        for (int r = 0; r < 4; ++r) acc2[t][r] = lrelu(acc2[t][r] + b2v);
    }
    float gv[4], bv[4];
    #pragma unroll
    for (int t = 0; t < 4; ++t) { gv[t] = gam[t * 16 + c]; bv[t] = bet[t * 16 + c]; }
    #pragma unroll
    for (int r = 0; r < 4; ++r) {
        float s = acc2[0][r] + acc2[1][r] + acc2[2][r] + acc2[3][r];
        s += __shfl_xor(s, 1); s += __shfl_xor(s, 2); s += __shfl_xor(s, 4); s += __shfl_xor(s, 8);
        const float mu = s * 0.015625f;
        float q = 0.f;
        #pragma unroll
        for (int t = 0; t < 4; ++t) { const float d = acc2[t][r] - mu; q = fmaf(d, d, q); }
        q += __shfl_xor(q, 1); q += __shfl_xor(q, 2); q += __shfl_xor(q, 4); q += __shfl_xor(q, 8);
        const float rs = rsqrtf(q * 0.015625f + 1e-5f);
        const int rl = wm * 16 + g * 4 + r;
        const int grow = row0 + rl;
        if (grow < E) {
            #pragma unroll
            for (int t = 0; t < 4; ++t) {
                const int col = t * 16 + c;
                const int off = rl * 64 + (((col >> 3) ^ (rl & 7)) << 3) + (col & 7);
                const float eo = bf16_to_f((unsigned short)Ab[off]) + bf16_to_f((unsigned short)Ab[4096 + off]);
                e[(long long)grow * 64 + col] = (acc2[t][r] - mu) * rs * gv[t] + bv[t] + eo;
            }
        }
    }
}

// ---------------- node update: n += LN(lrelu(lrelu(n@W1a + aggr@W1b + b1)@W2 + b2)) ----------------
__global__ __launch_bounds__(256) void k_node_mf(
    float* __restrict__ n, const float* __restrict__ aggr,
    const short* __restrict__ wfW1a, const short* __restrict__ wfW1b, const short* __restrict__ wfW2,
    const float* __restrict__ b1, const float* __restrict__ b2,
    const float* __restrict__ gam, const float* __restrict__ bet, int N)
{
    __shared__ short An[8192];
    __shared__ short Aa[8192];
    __shared__ short Hf[8192];
    const int row0 = blockIdx.x * 64;
    stageA64(n, row0, N, An);
    stageA64(aggr, row0, N, Aa);
    __syncthreads();
    const int lane = threadIdx.x & 63;
    const int wm = threadIdx.x >> 6;
    const int g = lane >> 4, c = lane & 15;
    const int rowA = wm * 16 + c;
    const f32x4 z4 = {0.f, 0.f, 0.f, 0.f};
    f32x4 acc[4];
    #pragma unroll
    for (int t = 0; t < 4; ++t) acc[t] = z4;
    gemm64(An, wfW1a, rowA, g, lane, acc);
    gemm64(Aa, wfW1b, rowA, g, lane, acc);
    #pragma unroll
    for (int t = 0; t < 4; ++t) {
        const int col = t * 16 + c;
        const float b1v = b1[col];
        #pragma unroll
        for (int r = 0; r < 4; ++r) {
            const int rl = wm * 16 + g * 4 + r;
            const float h = lrelu(acc[t][r] + b1v);
            unsigned short hi, lo; split2(h, hi, lo);
            const int off = rl * 64 + (((col >> 3) ^ (rl & 7)) << 3) + (col & 7);
            Hf[off] = (short)hi;
            Hf[4096 + off] = (short)lo;
        }
    }
    f32x4 acc2[4];
    #pragma unroll
    for (int t = 0; t < 4; ++t) acc2[t] = z4;
    gemm64(Hf, wfW2, rowA, g, lane, acc2);
    #pragma unroll
    for (int t = 0; t < 4; ++t) {
        const float b2v = b2[t * 16 + c];
        #pragma unroll
        for (int r = 0; r < 4; ++r) acc2[t][r] = lrelu(acc2[t][r] + b2v);
    }
    float gv[4], bv[4];
    #pragma unroll
    for (int t = 0; t < 4; ++t) { gv[t] = gam[t * 16 + c]; bv[t] = bet[t * 16 + c]; }
    #pragma unroll
    for (int r = 0; r < 4; ++r) {
        float s = acc2[0][r] + acc2[1][r] + acc2[2][r] + acc2[3][r];
        s += __shfl_xor(s, 1); s += __shfl_xor(s, 2); s += __shfl_xor(s, 4); s += __shfl_xor(s, 8);
        const float mu = s * 0.015625f;
        float q = 0.f;
        #pragma unroll
        for (int t = 0; t < 4; ++t) { const float d = acc2[t][r] - mu; q = fmaf(d, d, q); }
        q += __shfl_xor(q, 1); q += __shfl_xor(q, 2); q += __shfl_xor(q, 4); q += __shfl_xor(q, 8);
        const float rs = rsqrtf(q * 0.015625f + 1e-5f);
        const int rl = wm * 16 + g * 4 + r;
        const int grow = row0 + rl;
        if (grow < N) {
            #pragma unroll
            for (int t = 0; t < 4; ++t) {
                const int col = t * 16 + c;
                const int off = rl * 64 + (((col >> 3) ^ (rl & 7)) << 3) + (col & 7);
                const float no = bf16_to_f((unsigned short)An[off]) + bf16_to_f((unsigned short)An[4096 + off]);
                n[(long long)grow * 64 + col] = (acc2[t][r] - mu) * rs * gv[t] + bv[t] + no;
            }
        }
    }
}

// ================= VALU kernels (encoders / decoder / CSR / aggr) =================
template<int DIN>
__device__ __forceinline__ void stage_rows(const float* __restrict__ g, int nr, float* __restrict__ lx)
{
    const int total = nr * DIN;
    for (int idx = threadIdx.x * 4; idx < total; idx += BT * 4) {
        const float4 vv = *reinterpret_cast<const float4*>(g + idx);
        const int row = idx / DIN;
        const int k = idx - row * DIN;
        const int m = row & 31, p = m & 3;
        const float e0 = (p & 2) ? vv.z : vv.x;
        const float e1 = (p & 2) ? vv.w : vv.y;
        const float e2 = (p & 2) ? vv.x : vv.z;
        const float e3 = (p & 2) ? vv.y : vv.w;
        const float f0 = (p & 1) ? e1 : e0;
        const float f1 = (p & 1) ? e0 : e1;
        const float f2 = (p & 1) ? e3 : e2;
        const float f3 = (p & 1) ? e2 : e3;
        const int q = (row << 6) + ((k ^ m) & ~3);
        *reinterpret_cast<float4*>(lx + q) = make_float4(f0, f1, f2, f3);
    }
}

template<int DIN>
__device__ __forceinline__ void accum(const float* __restrict__ lx, int row,
                                      const float* __restrict__ W, float* __restrict__ acc)
{
    const int base = row << 6, m = row & 31;
    #pragma unroll 4
    for (int k = 0; k < DIN; ++k) {
        const float xv = lx[base + (k ^ m)];
        const float* wr = W + k * 64;
        #pragma unroll
        for (int j = 0; j < 64; ++j)
            acc[j] = fmaf(xv, wr[j], acc[j]);
    }
}

__device__ __forceinline__ void layernorm(float* __restrict__ a,
                                          const float* __restrict__ g, const float* __restrict__ be)
{
    float mu = 0.f;
    #pragma unroll
    for (int j = 0; j < 64; ++j) mu += a[j];
    mu *= 0.015625f;
    float var = 0.f;
    #pragma unroll
    for (int j = 0; j < 64; ++j) { const float d = a[j] - mu; var = fmaf(d, d, var); }
    var *= 0.015625f;
    const float rs = rsqrtf(var + 1e-5f);
    #pragma unroll
    for (int j = 0; j < 64; ++j) a[j] = (a[j] - mu) * rs * g[j] + be[j];
}

__device__ __forceinline__ void store_row64(float* __restrict__ dst, const float* __restrict__ a)
{
    #pragma unroll
    for (int q = 0; q < 16; ++q)
        reinterpret_cast<float4*>(dst)[q] = make_float4(a[4*q], a[4*q+1], a[4*q+2], a[4*q+3]);
}

template<int DIN>
__global__ __launch_bounds__(BT, 2) void k_encode(
    const float* __restrict__ x,
    const float* __restrict__ W1, const float* __restrict__ b1,
    const float* __restrict__ W2, const float* __restrict__ b2,
    const float* __restrict__ g, const float* __restrict__ be,
    float* __restrict__ out, int nrows)
{
    __shared__ float lx[BT * 64];
    const int row0 = blockIdx.x * BT;
    const int nr = min(BT, nrows - row0);
    stage_rows<DIN>(x + (long long)row0 * DIN, nr, lx);
    __syncthreads();
    const int row = threadIdx.x;
    if (row >= nr) return;
    float acc[64];
    #pragma unroll
    for (int j = 0; j < 64; ++j) acc[j] = b1[j];
    accum<DIN>(lx, row, W1, acc);
    const int base = row << 6, m = row & 31;
    #pragma unroll
    for (int k = 0; k < 64; ++k) lx[base + (k ^ m)] = lrelu(acc[k]);
    #pragma unroll
    for (int j = 0; j < 64; ++j) acc[j] = b2[j];
    accum<64>(lx, row, W2, acc);
    #pragma unroll
    for (int j = 0; j < 64; ++j) acc[j] = lrelu(acc[j]);
    layernorm(acc, g, be);
    store_row64(out + (long long)(row0 + row) * 64, acc);
}

__global__ void k_hist(const int* __restrict__ eidx, int* __restrict__ cnt, int E)
{
    int i = blockIdx.x * 256 + threadIdx.x;
    if (i < E) atomicAdd(&cnt[eidx[2 * i]], 1);
}

__global__ void k_scan1(const int* __restrict__ cnt, int* __restrict__ starts,
                        int* __restrict__ bsum, int n)
{
    __shared__ int sh[256];
    const int tid = threadIdx.x;
    const int i = blockIdx.x * 256 + tid;
    const int val = (i < n) ? cnt[i] : 0;
    sh[tid] = val; __syncthreads();
    for (int off = 1; off < 256; off <<= 1) {
        int t = (tid >= off) ? sh[tid - off] : 0;
        __syncthreads();
        sh[tid] += t;
        __syncthreads();
    }
    if (i < n) starts[i] = sh[tid] - val;
    if (tid == 255) bsum[blockIdx.x] = sh[255];
}

__global__ void k_scan2(int* __restrict__ bsum, int nb)
{
    __shared__ int sh[256];
    const int tid = threadIdx.x;
    const int val = (tid < nb) ? bsum[tid] : 0;
    sh[tid] = val; __syncthreads();
    for (int off = 1; off < 256; off <<= 1) {
        int t = (tid >= off) ? sh[tid - off] : 0;
        __syncthreads();
        sh[tid] += t;
        __syncthreads();
    }
    if (tid < nb) bsum[tid] = sh[tid] - val;
}

__global__ void k_scan3(int* __restrict__ starts, const int* __restrict__ bsum, int n)
{
    int i = blockIdx.x * 256 + threadIdx.x;
    if (i < n) starts[i] += bsum[blockIdx.x];
}

__global__ void k_scatter(const int* __restrict__ eidx, const int* __restrict__ starts,
                          int* __restrict__ cursor, int* __restrict__ csr, int E)
{
    int i = blockIdx.x * 256 + threadIdx.x;
    if (i < E) {
        const int s = eidx[2 * i];
        const int p = atomicAdd(&cursor[s], 1);
        csr[starts[s] + p] = i;
    }
}

__global__ __launch_bounds__(256) void k_aggr(
    const float* __restrict__ e, const int* __restrict__ starts, const int* __restrict__ cnt,
    const int* __restrict__ csr, float* __restrict__ aggr, int N)
{
    const int node = blockIdx.x * 4 + (threadIdx.x >> 6);
    if (node >= N) return;
    const int j = threadIdx.x & 63;
    const int st = starts[node], en = st + cnt[node];
    float a = 0.f;
    for (int t = st; t < en; ++t) {
        const int eid = csr[t];
        a += e[(long long)eid * 64 + j];
    }
    aggr[(long long)node * 64 + j] = a;
}

__global__ __launch_bounds__(BT, 2) void k_dec(
    const float* __restrict__ n, const float* __restrict__ W1, const float* __restrict__ b1,
    const float* __restrict__ W2, const float* __restrict__ b2,
    float* __restrict__ out, int nrows)
{
    __shared__ float lx[BT * 64];
    const int row0 = blockIdx.x * BT;
    const int nr = min(BT, nrows - row0);
    stage_rows<64>(n + (long long)row0 * 64, nr, lx);
    __syncthreads();
    const int row = threadIdx.x;
    if (row >= nr) return;
    float acc[64];
    #pragma unroll
    for (int j = 0; j < 64; ++j) acc[j] = b1[j];
    accum<64>(lx, row, W1, acc);
    const int base = row << 6, m = row & 31;
    #pragma unroll
    for (int k = 0; k < 64; ++k) lx[base + (k ^ m)] = lrelu(acc[k]);
    float o0 = b2[0], o1 = b2[1], o2 = b2[2];
    #pragma unroll 4
    for (int k = 0; k < 64; ++k) {
        const float h = lx[base + (k ^ m)];
        o0 = fmaf(h, W2[k * 3 + 0], o0);
        o1 = fmaf(h, W2[k * 3 + 1], o1);
        o2 = fmaf(h, W2[k * 3 + 2], o2);
    }
    float* op = out + (long long)(row0 + row) * 3;
    op[0] = o0; op[1] = o1; op[2] = o2;
}

extern "C" void kernel_launch(void* const* d_in, const int* in_sizes, int n_in,
                              void* d_out, int out_size, void* d_ws, size_t ws_size,
                              hipStream_t stream)
{
    (void)in_sizes; (void)n_in; (void)out_size; (void)ws_size;
    constexpr int N = 50000, E = 300000, L = 3;

    const float* nodes = (const float*)d_in[0];
    const float* edges = (const float*)d_in[1];
    const int*   eidx  = (const int*)d_in[2];
    const float* neW1 = (const float*)d_in[3];
    const float* neb1 = (const float*)d_in[4];
    const float* neW2 = (const float*)d_in[5];
    const float* neb2 = (const float*)d_in[6];
    const float* neg  = (const float*)d_in[7];
    const float* nebe = (const float*)d_in[8];
    const float* eeW1 = (const float*)d_in[9];
    const float* eeb1 = (const float*)d_in[10];
    const float* eeW2 = (const float*)d_in[11];
    const float* eeb2 = (const float*)d_in[12];
    const float* eeg  = (const float*)d_in[13];
    const float* eebe = (const float*)d_in[14];
    const float* nmW1 = (const float*)d_in[15];
    const float* nmb1 = (const float*)d_in[16];
    const float* nmW2 = (const float*)d_in[17];
    const float* nmb2 = (const float*)d_in[18];
    const float* nmg  = (const float*)d_in[19];
    const float* nmbe = (const float*)d_in[20];
    const float* emW1 = (const float*)d_in[21];
    const float* emb1 = (const float*)d_in[22];
    const float* emW2 = (const float*)d_in[23];
    const float* emb2 = (const float*)d_in[24];
    const float* emg  = (const float*)d_in[25];
    const float* embe = (const float*)d_in[26];
    const float* decW1 = (const float*)d_in[27];
    const float* decb1 = (const float*)d_in[28];
    const float* decW2 = (const float*)d_in[29];
    const float* decb2 = (const float*)d_in[30];

    // workspace: n | u(=aggr) | v | e | ints | wfrag
    float* n   = (float*)d_ws;                  // N*64
    float* u   = n + (size_t)N * 64;            // N*64
    float* v   = u + (size_t)N * 64;            // N*64
    float* e   = v + (size_t)N * 64;            // E*64
    int* cnt    = (int*)(e + (size_t)E * 64);   // N
    int* starts = cnt + N;                      // N
    int* csr    = starts + N;                   // E
    int* bsum   = csr + E;                      // 256
    int* cursor = bsum + 256;                   // N
    short* wf   = (short*)(cursor + N);         // 21 * 8192 shorts

    const int nbN = (N + BT - 1) / BT;
    const int nbE = (E + BT - 1) / BT;
    const int nbN64 = (N + 63) / 64;            // 782
    const int nbE64 = (E + 63) / 64;            // 4688

    // ---- weight fragment prep + CSR build ----
    k_prepw<<<21, 256, 0, stream>>>(emW1, emW2, nmW1, nmW2, wf);
    hipMemsetAsync(cnt, 0, (size_t)N * sizeof(int), stream);
    hipMemsetAsync(cursor, 0, (size_t)N * sizeof(int), stream);
    k_hist<<<nbE, 256, 0, stream>>>(eidx, cnt, E);
    k_scan1<<<nbN, 256, 0, stream>>>(cnt, starts, bsum, N);
    k_scan2<<<1, 256, 0, stream>>>(bsum, nbN);
    k_scan3<<<nbN, 256, 0, stream>>>(starts, bsum, N);
    k_scatter<<<nbE, 256, 0, stream>>>(eidx, starts, cursor, csr, E);

    // ---- encode ----
    k_encode<16><<<nbN, BT, 0, stream>>>(nodes, neW1, neb1, neW2, neb2, neg, nebe, n, N);
    k_encode<8> <<<nbE, BT, 0, stream>>>(edges, eeW1, eeb1, eeW2, eeb2, eeg, eebe, e, E);

    // ---- message-passing layers (MFMA) ----
    for (int i = 0; i < L; ++i) {
        const short* wl = wf + (size_t)i * 7 * 8192;
        k_uv_mf<<<nbN64, 256, 0, stream>>>(n, wl + 8192, wl + 2 * 8192, u, v, N);
        k_edge_mf<<<nbE64, 256, 0, stream>>>(e, eidx, u, v, wl, wl + 3 * 8192,
                                             emb1 + i * 64, emb2 + i * 64,
                                             emg + i * 64, embe + i * 64, E);
        k_aggr<<<(N + 3) / 4, 256, 0, stream>>>(e, starts, cnt, csr, u, N);  // u := aggr
        k_node_mf<<<nbN64, 256, 0, stream>>>(n, u, wl + 4 * 8192, wl + 5 * 8192, wl + 6 * 8192,
                                             nmb1 + i * 64, nmb2 + i * 64,
                                             nmg + i * 64, nmbe + i * 64, N);
    }
    k_dec<<<nbN, BT, 0, stream>>>(n, decW1, decb1, decW2, decb2, (float*)d_out, N);
}

// Round 4
// 455.475 us; speedup vs baseline: 8.6737x; 1.3037x over previous
//
#include <hip/hip_runtime.h>

constexpr int BT = 256;

typedef __attribute__((ext_vector_type(8))) short short8v;
typedef __attribute__((ext_vector_type(4))) short short4v;
typedef __attribute__((ext_vector_type(4))) float f32x4;

__device__ __forceinline__ float lrelu(float x) { return x >= 0.f ? x : 0.05f * x; }

__device__ __forceinline__ unsigned short bf16_rne(float x) {
    unsigned u = __float_as_uint(x);
    u += 0x7FFFu + ((u >> 16) & 1u);
    return (unsigned short)(u >> 16);
}
__device__ __forceinline__ float bf16_to_f(unsigned short h) {
    return __uint_as_float(((unsigned)h) << 16);
}
__device__ __forceinline__ void split2(float x, unsigned short& hi, unsigned short& lo) {
    hi = bf16_rne(x);
    lo = bf16_rne(x - bf16_to_f(hi));
}

// ================= MFMA machinery =================
// A-frag (M=16,K=32): lane holds A[row=lane&15][k=(lane>>4)*8+i]
// B-frag: lane holds B[k=(lane>>4)*8+i][col=lane&15]
// C/D: col=lane&15, row=(lane>>4)*4+reg
// LDS A layout per plane: A[row][k] shorts, 16B slots XOR-swizzled: slot = (k>>3)^(row&7)

__device__ __forceinline__ void stageA64(const float* __restrict__ src, int row0, int nrows,
                                         short* __restrict__ A)
{
    for (int q = threadIdx.x; q < 1024; q += 256) {
        const int row = q >> 4;
        const int k0 = (q & 15) << 2;
        const int grow = row0 + row;
        float4 x = (grow < nrows) ? *reinterpret_cast<const float4*>(src + (long long)grow * 64 + k0)
                                  : make_float4(0.f, 0.f, 0.f, 0.f);
        unsigned short h0,h1,h2,h3,l0,l1,l2,l3;
        split2(x.x, h0, l0); split2(x.y, h1, l1); split2(x.z, h2, l2); split2(x.w, h3, l3);
        const int off = row * 64 + ((((k0 >> 3) ^ (row & 7))) << 3) + (k0 & 7);
        short4v hv; hv[0]=(short)h0; hv[1]=(short)h1; hv[2]=(short)h2; hv[3]=(short)h3;
        short4v lv; lv[0]=(short)l0; lv[1]=(short)l1; lv[2]=(short)l2; lv[3]=(short)l3;
        *reinterpret_cast<short4v*>(A + off) = hv;
        *reinterpret_cast<short4v*>(A + 4096 + off) = lv;
    }
}

// acc[t] += X[16rows][64] @ W[64][64] (split-bf16 3-term); A = LDS hi plane (lo at +4096)
__device__ __forceinline__ void gemm64(const short* __restrict__ A, const short* __restrict__ wf,
                                       int row, int g, int lane, f32x4* __restrict__ acc)
{
    #pragma unroll
    for (int s = 0; s < 2; ++s) {
        const int k8 = s * 4 + g;
        const int aoff = row * 64 + ((k8 ^ (row & 7)) << 3);
        const short8v a_hi = *reinterpret_cast<const short8v*>(A + aoff);
        const short8v a_lo = *reinterpret_cast<const short8v*>(A + 4096 + aoff);
        #pragma unroll
        for (int t = 0; t < 4; ++t) {
            const short8v b_hi = *reinterpret_cast<const short8v*>(wf + ((s*4+t)*2+0)*512 + lane*8);
            const short8v b_lo = *reinterpret_cast<const short8v*>(wf + ((s*4+t)*2+1)*512 + lane*8);
            acc[t] = __builtin_amdgcn_mfma_f32_16x16x32_bf16(a_hi, b_hi, acc[t], 0, 0, 0);
            acc[t] = __builtin_amdgcn_mfma_f32_16x16x32_bf16(a_lo, b_hi, acc[t], 0, 0, 0);
            acc[t] = __builtin_amdgcn_mfma_f32_16x16x32_bf16(a_hi, b_lo, acc[t], 0, 0, 0);
        }
    }
}

// Preformat 64x64 fp32 W[k][col] chunks -> hi/lo B-fragments.
// cid<21: layer=cid/7, j=cid%7: [A,B,C,W2e,W1a,W1b,W2n]; cid 21=eeW2, 22=neW2, 23=decW1
__global__ void k_prepw(const float* __restrict__ emW1, const float* __restrict__ emW2,
                        const float* __restrict__ nmW1, const float* __restrict__ nmW2,
                        const float* __restrict__ eeW2, const float* __restrict__ neW2,
                        const float* __restrict__ decW1,
                        short* __restrict__ wf)
{
    const int cid = blockIdx.x;
    const float* src;
    if (cid < 21) {
        const int layer = cid / 7, j = cid % 7;
        src =
            j == 0 ? emW1 + (size_t)layer * 12288 :
            j == 1 ? emW1 + (size_t)layer * 12288 + 4096 :
            j == 2 ? emW1 + (size_t)layer * 12288 + 8192 :
            j == 3 ? emW2 + (size_t)layer * 4096 :
            j == 4 ? nmW1 + (size_t)layer * 8192 :
            j == 5 ? nmW1 + (size_t)layer * 8192 + 4096 :
                     nmW2 + (size_t)layer * 4096;
    } else {
        src = (cid == 21) ? eeW2 : (cid == 22) ? neW2 : decW1;
    }
    short* dst = wf + (size_t)cid * 8192;
    for (int fr = threadIdx.x; fr < 1024; fr += 256) {
        const int lane = fr & 63;
        const int stp = fr >> 6;
        const int p = stp & 1;
        const int st = stp >> 1;
        const int s = st >> 2, t = st & 3;
        const int col = t * 16 + (lane & 15);
        const int k0 = s * 32 + (lane >> 4) * 8;
        short8v o;
        #pragma unroll
        for (int i = 0; i < 8; ++i) {
            const float w = src[(k0 + i) * 64 + col];
            const unsigned short hi = bf16_rne(w);
            o[i] = (short)(p ? bf16_rne(w - bf16_to_f(hi)) : hi);
        }
        *reinterpret_cast<short8v*>(dst + fr * 8) = o;
    }
}

// ---------------- encoder: out = LN(lrelu(lrelu(x@W1+b1)@W2+b2)); layer1 VALU, layer2 MFMA ----
// PERM: read x rows via csr[] gather (edge stream permuted to CSR order)
template<int DIN, bool PERM>
__global__ __launch_bounds__(256) void k_enc_mf(
    const float* __restrict__ x, const int* __restrict__ csr,
    const float* __restrict__ W1, const float* __restrict__ b1,
    const short* __restrict__ wfW2, const float* __restrict__ b2,
    const float* __restrict__ gam, const float* __restrict__ bet,
    float* __restrict__ out, int nrows)
{
    __shared__ short Hf[8192];
    const int row0 = blockIdx.x * 64;
    const int lane = threadIdx.x & 63;
    const int wm = threadIdx.x >> 6;
    const int g = lane >> 4, c = lane & 15;
    const int rowA = wm * 16 + c;

    long long orig[4];
    #pragma unroll
    for (int r = 0; r < 4; ++r) {
        const int grow = row0 + wm * 16 + g * 4 + r;
        orig[r] = (grow < nrows) ? (long long)(PERM ? csr[grow] : grow) : -1;
    }

    const f32x4 z4 = {0.f, 0.f, 0.f, 0.f};
    f32x4 acc[4];
    #pragma unroll
    for (int t = 0; t < 4; ++t) acc[t] = z4;

    #pragma unroll
    for (int kq = 0; kq < DIN / 4; ++kq) {
        float xv[4][4];
        #pragma unroll
        for (int r = 0; r < 4; ++r) {
            float4 t4 = make_float4(0.f, 0.f, 0.f, 0.f);
            if (orig[r] >= 0)
                t4 = *reinterpret_cast<const float4*>(x + orig[r] * DIN + kq * 4);
            xv[r][0] = t4.x; xv[r][1] = t4.y; xv[r][2] = t4.z; xv[r][3] = t4.w;
        }
        #pragma unroll
        for (int i = 0; i < 4; ++i) {
            const int k = kq * 4 + i;
            float wv[4];
            #pragma unroll
            for (int t = 0; t < 4; ++t) wv[t] = W1[k * 64 + t * 16 + c];
            #pragma unroll
            for (int t = 0; t < 4; ++t)
                #pragma unroll
                for (int r = 0; r < 4; ++r)
                    acc[t][r] = fmaf(xv[r][i], wv[t], acc[t][r]);
        }
    }

    // bias + lrelu -> split -> Hf (own wave's rows; no barrier needed)
    #pragma unroll
    for (int t = 0; t < 4; ++t) {
        const int col = t * 16 + c;
        const float b1v = b1[col];
        #pragma unroll
        for (int r = 0; r < 4; ++r) {
            const int rl = wm * 16 + g * 4 + r;
            const float h = lrelu(acc[t][r] + b1v);
            unsigned short hi, lo; split2(h, hi, lo);
            const int off = rl * 64 + (((col >> 3) ^ (rl & 7)) << 3) + (col & 7);
            Hf[off] = (short)hi;
            Hf[4096 + off] = (short)lo;
        }
    }

    f32x4 acc2[4];
    #pragma unroll
    for (int t = 0; t < 4; ++t) acc2[t] = z4;
    gemm64(Hf, wfW2, rowA, g, lane, acc2);

    #pragma unroll
    for (int t = 0; t < 4; ++t) {
        const float b2v = b2[t * 16 + c];
        #pragma unroll
        for (int r = 0; r < 4; ++r) acc2[t][r] = lrelu(acc2[t][r] + b2v);
    }
    float gv[4], bv[4];
    #pragma unroll
    for (int t = 0; t < 4; ++t) { gv[t] = gam[t * 16 + c]; bv[t] = bet[t * 16 + c]; }
    #pragma unroll
    for (int r = 0; r < 4; ++r) {
        float s = acc2[0][r] + acc2[1][r] + acc2[2][r] + acc2[3][r];
        s += __shfl_xor(s, 1); s += __shfl_xor(s, 2); s += __shfl_xor(s, 4); s += __shfl_xor(s, 8);
        const float mu = s * 0.015625f;
        float q = 0.f;
        #pragma unroll
        for (int t = 0; t < 4; ++t) { const float d = acc2[t][r] - mu; q = fmaf(d, d, q); }
        q += __shfl_xor(q, 1); q += __shfl_xor(q, 2); q += __shfl_xor(q, 4); q += __shfl_xor(q, 8);
        const float rs = rsqrtf(q * 0.015625f + 1e-5f);
        const int grow = row0 + wm * 16 + g * 4 + r;
        if (grow < nrows) {
            #pragma unroll
            for (int t = 0; t < 4; ++t)
                out[(long long)grow * 64 + t * 16 + c] = (acc2[t][r] - mu) * rs * gv[t] + bv[t];
        }
    }
}

// ---------------- u = n@B, v = n@C ----------------
__global__ __launch_bounds__(256) void k_uv_mf(
    const float* __restrict__ n, const short* __restrict__ wfB, const short* __restrict__ wfC,
    float* __restrict__ u, float* __restrict__ v, int N)
{
    __shared__ short Ab[8192];
    const int row0 = blockIdx.x * 64;
    stageA64(n, row0, N, Ab);
    __syncthreads();
    const int lane = threadIdx.x & 63;
    const int wm = threadIdx.x >> 6;
    const int g = lane >> 4, c = lane & 15;
    const int rowA = wm * 16 + c;
    const f32x4 z4 = {0.f, 0.f, 0.f, 0.f};
    f32x4 acc[4];
    #pragma unroll
    for (int t = 0; t < 4; ++t) acc[t] = z4;
    gemm64(Ab, wfB, rowA, g, lane, acc);
    #pragma unroll
    for (int r = 0; r < 4; ++r) {
        const int grow = row0 + wm * 16 + g * 4 + r;
        if (grow < N) {
            #pragma unroll
            for (int t = 0; t < 4; ++t) u[(long long)grow * 64 + t * 16 + c] = acc[t][r];
        }
    }
    #pragma unroll
    for (int t = 0; t < 4; ++t) acc[t] = z4;
    gemm64(Ab, wfC, rowA, g, lane, acc);
    #pragma unroll
    for (int r = 0; r < 4; ++r) {
        const int grow = row0 + wm * 16 + g * 4 + r;
        if (grow < N) {
            #pragma unroll
            for (int t = 0; t < 4; ++t) v[(long long)grow * 64 + t * 16 + c] = acc[t][r];
        }
    }
}

// ---------------- edge update (CSR-permuted order): e += LN(...); sp/rp per position ----------------
__global__ __launch_bounds__(256) void k_edge_mf(
    float* __restrict__ e, const int* __restrict__ sp, const int* __restrict__ rp,
    const float* __restrict__ u, const float* __restrict__ v,
    const short* __restrict__ wfA, const short* __restrict__ wfW2,
    const float* __restrict__ b1, const float* __restrict__ b2,
    const float* __restrict__ gam, const float* __restrict__ bet, int E)
{
    __shared__ short Ab[8192];
    __shared__ short Hf[8192];
    const int row0 = blockIdx.x * 64;
    stageA64(e, row0, E, Ab);
    __syncthreads();
    const int lane = threadIdx.x & 63;
    const int wm = threadIdx.x >> 6;
    const int g = lane >> 4, c = lane & 15;
    const int rowA = wm * 16 + c;
    int sidx[4], ridx[4];
    #pragma unroll
    for (int r = 0; r < 4; ++r) {
        const int grow = row0 + wm * 16 + g * 4 + r;
        if (grow < E) { sidx[r] = sp[grow]; ridx[r] = rp[grow]; }
        else          { sidx[r] = 0; ridx[r] = 0; }
    }
    const f32x4 z4 = {0.f, 0.f, 0.f, 0.f};
    f32x4 acc[4];
    #pragma unroll
    for (int t = 0; t < 4; ++t) acc[t] = z4;
    gemm64(Ab, wfA, rowA, g, lane, acc);
    #pragma unroll
    for (int t = 0; t < 4; ++t) {
        const int col = t * 16 + c;
        const float b1v = b1[col];
        #pragma unroll
        for (int r = 0; r < 4; ++r)
            acc[t][r] += b1v + u[(long long)sidx[r] * 64 + col] + v[(long long)ridx[r] * 64 + col];
    }
    #pragma unroll
    for (int t = 0; t < 4; ++t) {
        const int col = t * 16 + c;
        #pragma unroll
        for (int r = 0; r < 4; ++r) {
            const int rl = wm * 16 + g * 4 + r;
            const float h = lrelu(acc[t][r]);
            unsigned short hi, lo; split2(h, hi, lo);
            const int off = rl * 64 + (((col >> 3) ^ (rl & 7)) << 3) + (col & 7);
            Hf[off] = (short)hi;
            Hf[4096 + off] = (short)lo;
        }
    }
    f32x4 acc2[4];
    #pragma unroll
    for (int t = 0; t < 4; ++t) acc2[t] = z4;
    gemm64(Hf, wfW2, rowA, g, lane, acc2);
    #pragma unroll
    for (int t = 0; t < 4; ++t) {
        const float b2v = b2[t * 16 + c];
        #pragma unroll
        for (int r = 0; r < 4; ++r) acc2[t][r] = lrelu(acc2[t][r] + b2v);
    }
    float gv[4], bv[4];
    #pragma unroll
    for (int t = 0; t < 4; ++t) { gv[t] = gam[t * 16 + c]; bv[t] = bet[t * 16 + c]; }
    #pragma unroll
    for (int r = 0; r < 4; ++r) {
        float s = acc2[0][r] + acc2[1][r] + acc2[2][r] + acc2[3][r];
        s += __shfl_xor(s, 1); s += __shfl_xor(s, 2); s += __shfl_xor(s, 4); s += __shfl_xor(s, 8);
        const float mu = s * 0.015625f;
        float q = 0.f;
        #pragma unroll
        for (int t = 0; t < 4; ++t) { const float d = acc2[t][r] - mu; q = fmaf(d, d, q); }
        q += __shfl_xor(q, 1); q += __shfl_xor(q, 2); q += __shfl_xor(q, 4); q += __shfl_xor(q, 8);
        const float rs = rsqrtf(q * 0.015625f + 1e-5f);
        const int rl = wm * 16 + g * 4 + r;
        const int grow = row0 + rl;
        if (grow < E) {
            #pragma unroll
            for (int t = 0; t < 4; ++t) {
                const int col = t * 16 + c;
                const int off = rl * 64 + (((col >> 3) ^ (rl & 7)) << 3) + (col & 7);
                const float eo = bf16_to_f((unsigned short)Ab[off]) + bf16_to_f((unsigned short)Ab[4096 + off]);
                e[(long long)grow * 64 + col] = (acc2[t][r] - mu) * rs * gv[t] + bv[t] + eo;
            }
        }
    }
}

// ---------------- node update ----------------
__global__ __launch_bounds__(256) void k_node_mf(
    float* __restrict__ n, const float* __restrict__ aggr,
    const short* __restrict__ wfW1a, const short* __restrict__ wfW1b, const short* __restrict__ wfW2,
    const float* __restrict__ b1, const float* __restrict__ b2,
    const float* __restrict__ gam, const float* __restrict__ bet, int N)
{
    __shared__ short An[8192];
    __shared__ short Aa[8192];
    __shared__ short Hf[8192];
    const int row0 = blockIdx.x * 64;
    stageA64(n, row0, N, An);
    stageA64(aggr, row0, N, Aa);
    __syncthreads();
    const int lane = threadIdx.x & 63;
    const int wm = threadIdx.x >> 6;
    const int g = lane >> 4, c = lane & 15;
    const int rowA = wm * 16 + c;
    const f32x4 z4 = {0.f, 0.f, 0.f, 0.f};
    f32x4 acc[4];
    #pragma unroll
    for (int t = 0; t < 4; ++t) acc[t] = z4;
    gemm64(An, wfW1a, rowA, g, lane, acc);
    gemm64(Aa, wfW1b, rowA, g, lane, acc);
    #pragma unroll
    for (int t = 0; t < 4; ++t) {
        const int col = t * 16 + c;
        const float b1v = b1[col];
        #pragma unroll
        for (int r = 0; r < 4; ++r) {
            const int rl = wm * 16 + g * 4 + r;
            const float h = lrelu(acc[t][r] + b1v);
            unsigned short hi, lo; split2(h, hi, lo);
            const int off = rl * 64 + (((col >> 3) ^ (rl & 7)) << 3) + (col & 7);
            Hf[off] = (short)hi;
            Hf[4096 + off] = (short)lo;
        }
    }
    f32x4 acc2[4];
    #pragma unroll
    for (int t = 0; t < 4; ++t) acc2[t] = z4;
    gemm64(Hf, wfW2, rowA, g, lane, acc2);
    #pragma unroll
    for (int t = 0; t < 4; ++t) {
        const float b2v = b2[t * 16 + c];
        #pragma unroll
        for (int r = 0; r < 4; ++r) acc2[t][r] = lrelu(acc2[t][r] + b2v);
    }
    float gv[4], bv[4];
    #pragma unroll
    for (int t = 0; t < 4; ++t) { gv[t] = gam[t * 16 + c]; bv[t] = bet[t * 16 + c]; }
    #pragma unroll
    for (int r = 0; r < 4; ++r) {
        float s = acc2[0][r] + acc2[1][r] + acc2[2][r] + acc2[3][r];
        s += __shfl_xor(s, 1); s += __shfl_xor(s, 2); s += __shfl_xor(s, 4); s += __shfl_xor(s, 8);
        const float mu = s * 0.015625f;
        float q = 0.f;
        #pragma unroll
        for (int t = 0; t < 4; ++t) { const float d = acc2[t][r] - mu; q = fmaf(d, d, q); }
        q += __shfl_xor(q, 1); q += __shfl_xor(q, 2); q += __shfl_xor(q, 4); q += __shfl_xor(q, 8);
        const float rs = rsqrtf(q * 0.015625f + 1e-5f);
        const int rl = wm * 16 + g * 4 + r;
        const int grow = row0 + rl;
        if (grow < N) {
            #pragma unroll
            for (int t = 0; t < 4; ++t) {
                const int col = t * 16 + c;
                const int off = rl * 64 + (((col >> 3) ^ (rl & 7)) << 3) + (col & 7);
                const float no = bf16_to_f((unsigned short)An[off]) + bf16_to_f((unsigned short)An[4096 + off]);
                n[(long long)grow * 64 + col] = (acc2[t][r] - mu) * rs * gv[t] + bv[t] + no;
            }
        }
    }
}

// ---------------- decoder: MFMA layer1 + VALU tail (OUT=3) ----------------
__global__ __launch_bounds__(256) void k_dec_mf(
    const float* __restrict__ n, const short* __restrict__ wfW1, const float* __restrict__ b1,
    const float* __restrict__ W2, const float* __restrict__ b2,
    float* __restrict__ out, int N)
{
    __shared__ short An[8192];
    __shared__ float hrow[4096];
    const int row0 = blockIdx.x * 64;
    stageA64(n, row0, N, An);
    __syncthreads();
    const int lane = threadIdx.x & 63;
    const int wm = threadIdx.x >> 6;
    const int g = lane >> 4, c = lane & 15;
    const int rowA = wm * 16 + c;
    const f32x4 z4 = {0.f, 0.f, 0.f, 0.f};
    f32x4 acc[4];
    #pragma unroll
    for (int t = 0; t < 4; ++t) acc[t] = z4;
    gemm64(An, wfW1, rowA, g, lane, acc);
    #pragma unroll
    for (int t = 0; t < 4; ++t) {
        const int col = t * 16 + c;
        const float b1v = b1[col];
        #pragma unroll
        for (int r = 0; r < 4; ++r) {
            const int rl = wm * 16 + g * 4 + r;
            hrow[rl * 64 + (col ^ (rl & 31))] = lrelu(acc[t][r] + b1v);
        }
    }
    __syncthreads();
    const int row = threadIdx.x >> 2, o = threadIdx.x & 3;
    if (o < 3 && row0 + row < N) {
        float s = b2[o];
        #pragma unroll 8
        for (int k = 0; k < 64; ++k)
            s = fmaf(hrow[row * 64 + (k ^ (row & 31))], W2[k * 3 + o], s);
        out[(long long)(row0 + row) * 3 + o] = s;
    }
}

// ================= CSR build =================
__global__ void k_hist(const int* __restrict__ eidx, int* __restrict__ cnt, int E)
{
    int i = blockIdx.x * 256 + threadIdx.x;
    if (i < E) atomicAdd(&cnt[eidx[2 * i]], 1);
}

__global__ void k_scan1(const int* __restrict__ cnt, int* __restrict__ starts,
                        int* __restrict__ bsum, int n)
{
    __shared__ int sh[256];
    const int tid = threadIdx.x;
    const int i = blockIdx.x * 256 + tid;
    const int val = (i < n) ? cnt[i] : 0;
    sh[tid] = val; __syncthreads();
    for (int off = 1; off < 256; off <<= 1) {
        int t = (tid >= off) ? sh[tid - off] : 0;
        __syncthreads();
        sh[tid] += t;
        __syncthreads();
    }
    if (i < n) starts[i] = sh[tid] - val;
    if (tid == 255) bsum[blockIdx.x] = sh[255];
}

__global__ void k_scan2(int* __restrict__ bsum, int nb)
{
    __shared__ int sh[256];
    const int tid = threadIdx.x;
    const int val = (tid < nb) ? bsum[tid] : 0;
    sh[tid] = val; __syncthreads();
    for (int off = 1; off < 256; off <<= 1) {
        int t = (tid >= off) ? sh[tid - off] : 0;
        __syncthreads();
        sh[tid] += t;
        __syncthreads();
    }
    if (tid < nb) bsum[tid] = sh[tid] - val;
}

__global__ void k_scan3(int* __restrict__ starts, const int* __restrict__ bsum, int n)
{
    int i = blockIdx.x * 256 + threadIdx.x;
    if (i < n) starts[i] += bsum[blockIdx.x];
}

// scatter: csr position for each edge; also emit per-position source/receiver
__global__ void k_scatter(const int* __restrict__ eidx, const int* __restrict__ starts,
                          int* __restrict__ cursor, int* __restrict__ csr,
                          int* __restrict__ sp, int* __restrict__ rp, int E)
{
    int i = blockIdx.x * 256 + threadIdx.x;
    if (i < E) {
        const int s = eidx[2 * i];
        const int p = atomicAdd(&cursor[s], 1);
        const int q = starts[s] + p;
        csr[q] = i;
        sp[q] = s;
        rp[q] = eidx[2 * i + 1];
    }
}

// aggregation over CSR-ordered e: fully sequential reads
__global__ __launch_bounds__(256) void k_aggr(
    const float* __restrict__ e, const int* __restrict__ starts, const int* __restrict__ cnt,
    float* __restrict__ aggr, int N)
{
    const int node = blockIdx.x * 4 + (threadIdx.x >> 6);
    if (node >= N) return;
    const int j = threadIdx.x & 63;
    const int st = starts[node], en = st + cnt[node];
    float a = 0.f;
    for (int t = st; t < en; ++t)
        a += e[(long long)t * 64 + j];
    aggr[(long long)node * 64 + j] = a;
}

extern "C" void kernel_launch(void* const* d_in, const int* in_sizes, int n_in,
                              void* d_out, int out_size, void* d_ws, size_t ws_size,
                              hipStream_t stream)
{
    (void)in_sizes; (void)n_in; (void)out_size; (void)ws_size;
    constexpr int N = 50000, E = 300000, L = 3;

    const float* nodes = (const float*)d_in[0];
    const float* edges = (const float*)d_in[1];
    const int*   eidx  = (const int*)d_in[2];
    const float* neW1 = (const float*)d_in[3];
    const float* neb1 = (const float*)d_in[4];
    const float* neW2 = (const float*)d_in[5];
    const float* neb2 = (const float*)d_in[6];
    const float* neg  = (const float*)d_in[7];
    const float* nebe = (const float*)d_in[8];
    const float* eeW1 = (const float*)d_in[9];
    const float* eeb1 = (const float*)d_in[10];
    const float* eeW2 = (const float*)d_in[11];
    const float* eeb2 = (const float*)d_in[12];
    const float* eeg  = (const float*)d_in[13];
    const float* eebe = (const float*)d_in[14];
    const float* nmW1 = (const float*)d_in[15];
    const float* nmb1 = (const float*)d_in[16];
    const float* nmW2 = (const float*)d_in[17];
    const float* nmb2 = (const float*)d_in[18];
    const float* nmg  = (const float*)d_in[19];
    const float* nmbe = (const float*)d_in[20];
    const float* emW1 = (const float*)d_in[21];
    const float* emb1 = (const float*)d_in[22];
    const float* emW2 = (const float*)d_in[23];
    const float* emb2 = (const float*)d_in[24];
    const float* emg  = (const float*)d_in[25];
    const float* embe = (const float*)d_in[26];
    const float* decW1 = (const float*)d_in[27];
    const float* decb1 = (const float*)d_in[28];
    const float* decW2 = (const float*)d_in[29];
    const float* decb2 = (const float*)d_in[30];

    // workspace: n | u(=aggr) | v | e | ints | sp | rp | wf
    float* n   = (float*)d_ws;                  // N*64
    float* u   = n + (size_t)N * 64;            // N*64
    float* v   = u + (size_t)N * 64;            // N*64
    float* e   = v + (size_t)N * 64;            // E*64
    int* cnt    = (int*)(e + (size_t)E * 64);   // N
    int* starts = cnt + N;                      // N
    int* csr    = starts + N;                   // E
    int* bsum   = csr + E;                      // 256
    int* cursor = bsum + 256;                   // N
    int* sp     = cursor + N;                   // E
    int* rp     = sp + E;                       // E
    short* wf   = (short*)(rp + E);             // 24 * 8192 shorts

    const int nbN = (N + BT - 1) / BT;
    const int nbE = (E + BT - 1) / BT;
    const int nbN64 = (N + 63) / 64;            // 782
    const int nbE64 = (E + 63) / 64;            // 4688

    const short* wfEE  = wf + (size_t)21 * 8192;
    const short* wfNE  = wf + (size_t)22 * 8192;
    const short* wfDec = wf + (size_t)23 * 8192;

    // ---- weight fragment prep + CSR build ----
    k_prepw<<<24, 256, 0, stream>>>(emW1, emW2, nmW1, nmW2, eeW2, neW2, decW1, wf);
    hipMemsetAsync(cnt, 0, (size_t)N * sizeof(int), stream);
    hipMemsetAsync(cursor, 0, (size_t)N * sizeof(int), stream);
    k_hist<<<nbE, 256, 0, stream>>>(eidx, cnt, E);
    k_scan1<<<nbN, 256, 0, stream>>>(cnt, starts, bsum, N);
    k_scan2<<<1, 256, 0, stream>>>(bsum, nbN);
    k_scan3<<<nbN, 256, 0, stream>>>(starts, bsum, N);
    k_scatter<<<nbE, 256, 0, stream>>>(eidx, starts, cursor, csr, sp, rp, E);

    // ---- encode (node: identity order; edge: CSR-permuted order) ----
    k_enc_mf<16, false><<<nbN64, 256, 0, stream>>>(nodes, nullptr, neW1, neb1, wfNE,
                                                   neb2, neg, nebe, n, N);
    k_enc_mf<8, true><<<nbE64, 256, 0, stream>>>(edges, csr, eeW1, eeb1, wfEE,
                                                 eeb2, eeg, eebe, e, E);

    // ---- message-passing layers ----
    for (int i = 0; i < L; ++i) {
        const short* wl = wf + (size_t)i * 7 * 8192;
        k_uv_mf<<<nbN64, 256, 0, stream>>>(n, wl + 8192, wl + 2 * 8192, u, v, N);
        k_edge_mf<<<nbE64, 256, 0, stream>>>(e, sp, rp, u, v, wl, wl + 3 * 8192,
                                             emb1 + i * 64, emb2 + i * 64,
                                             emg + i * 64, embe + i * 64, E);
        k_aggr<<<(N + 3) / 4, 256, 0, stream>>>(e, starts, cnt, u, N);  // u := aggr
        k_node_mf<<<nbN64, 256, 0, stream>>>(n, u, wl + 4 * 8192, wl + 5 * 8192, wl + 6 * 8192,
                                             nmb1 + i * 64, nmb2 + i * 64,
                                             nmg + i * 64, nmbe + i * 64, N);
    }
    k_dec_mf<<<nbN64, 256, 0, stream>>>(n, wfDec, decb1, decW2, decb2, (float*)d_out, N);
}